// Round 11
// baseline (307.370 us; speedup 1.0000x reference)
//
#include <hip/hip_runtime.h>
#include <math.h>

#define BATCH 4096
#define NC    8192
#define DIM   512
#define KEXP  5
#define NCAND 10

using bf16x8 = __attribute__((ext_vector_type(8))) short;
using f32x4  = __attribute__((ext_vector_type(4))) float;
typedef unsigned long long u64;

// module-scope device buffers (no hipMalloc; deterministic, rewritten every call)
__device__ unsigned short g_zbf[BATCH * DIM];   // 4 MB bf16(z)
__device__ unsigned short g_cbf[NC * DIM];      // 8 MB bf16(centers)
__device__ float g_z2[BATCH];
__device__ float g_c2[NC];
__device__ float g_dots[(size_t)BATCH * NC];    // 134 MB raw dot products

__device__ __forceinline__ unsigned short rtne_bf16(float f) {
  unsigned u = __float_as_uint(f);
  u += 0x7FFFu + ((u >> 16) & 1u);
  return (unsigned short)(u >> 16);
}

__device__ __forceinline__ void gload16(const void* g, void* l) {
  __builtin_amdgcn_global_load_lds(
      (const __attribute__((address_space(1))) void*)g,
      (__attribute__((address_space(3))) void*)l, 16, 0, 0);
}

// ---------------------------------------------------------------------------
// Kernel 0: f32 -> bf16 (RTN) conversion FUSED with f64 row-norms.
// ---------------------------------------------------------------------------
__global__ __launch_bounds__(256) void convert_kernel(const float* __restrict__ z,
                                                      const float* __restrict__ c) {
  const size_t i = ((size_t)blockIdx.x * 256 + threadIdx.x) * 8;
  const size_t zn = (size_t)BATCH * DIM;
  const float* src;
  unsigned short* dst;
  float* ndst;
  size_t off;
  if (i < zn) { src = z; dst = g_zbf; ndst = g_z2; off = i; }
  else        { src = c; dst = g_cbf; ndst = g_c2; off = i - zn; }
  float4 a = *(const float4*)(src + off);
  float4 b = *(const float4*)(src + off + 4);
  uint4 o;
  o.x = (unsigned)rtne_bf16(a.x) | ((unsigned)rtne_bf16(a.y) << 16);
  o.y = (unsigned)rtne_bf16(a.z) | ((unsigned)rtne_bf16(a.w) << 16);
  o.z = (unsigned)rtne_bf16(b.x) | ((unsigned)rtne_bf16(b.y) << 16);
  o.w = (unsigned)rtne_bf16(b.z) | ((unsigned)rtne_bf16(b.w) << 16);
  *(uint4*)(dst + off) = o;

  double s = (double)a.x * a.x + (double)a.y * a.y + (double)a.z * a.z + (double)a.w * a.w +
             (double)b.x * b.x + (double)b.y * b.y + (double)b.z * b.z + (double)b.w * b.w;
#pragma unroll
  for (int sh = 32; sh > 0; sh >>= 1) s += __shfl_xor(s, sh);
  if ((threadIdx.x & 63) == 0) ndst[off / DIM] = (float)s;
}

// ---------------------------------------------------------------------------
// Kernel 2a: GEMM -> raw dots, round-6 structure (best measured), but with
// PERFECTLY LINEAR stores: 16 dwordx4/thread, 1 KB contiguous per wave-instr.
// Swapped operands mfma(fb, fa): C reg-dim = att cols -> a 16B reg chunk is
// 4 consecutive att cols. Dump layout per 128x128 tile (tile_id = tr*64+tc):
//   float off = tile_id*16384 + (wv*16 + j*4 + i)*256 + lane*4 + r
// where row_local = wm*64+i*16+(lane&15), col_local = wn*64+j*16+(lane>>4)*4+r.
// ---------------------------------------------------------------------------
#define BM  128
#define BN  128
#define BKK 64

__global__ __launch_bounds__(256) void gemm_dots() {
  __shared__ __align__(16) unsigned short Ah[BM * BKK];
  __shared__ __align__(16) unsigned short Bh[BM * BKK];

  const int tid  = threadIdx.x;
  const int lane = tid & 63;
  const int wid  = tid >> 6;
  const int wm   = wid >> 1;
  const int wn   = wid & 1;

  const int flat = blockIdx.x;
  const int swz  = (flat & 7) * 256 + (flat >> 3);
  const int tile_c = swz & 63;
  const int tile_r = swz >> 6;
  const int col0 = tile_c * BN;
  const int row0 = tile_r * BM;

  f32x4 acc[4][4] = {};   // acc[j][i]

  const unsigned short* Ag = g_zbf + (size_t)row0 * DIM;
  const unsigned short* Bg = g_cbf + (size_t)col0 * DIM;

  const int crow = lane >> 3;
  const int gsw  = (lane & 7) ^ crow;

  for (int k0 = 0; k0 < DIM; k0 += BKK) {
#pragma unroll
    for (int j = 0; j < 4; ++j) {
      const int base_row = (wid * 4 + j) * 8;
      const int r = base_row + crow;
      gload16(Ag + (size_t)r * DIM + k0 + gsw * 8, Ah + base_row * 64);
      gload16(Bg + (size_t)r * DIM + k0 + gsw * 8, Bh + base_row * 64);
    }
    __syncthreads();

#pragma unroll
    for (int kk = 0; kk < 2; ++kk) {
      bf16x8 fa[4], fb[4];
#pragma unroll
      for (int i = 0; i < 4; ++i) {
        const int r = wm * 64 + i * 16 + (lane & 15);
        const int g = (kk * 4 + (lane >> 4)) ^ (r & 7);
        fa[i] = *(const bf16x8*)((const char*)Ah + r * 128 + g * 16);
      }
#pragma unroll
      for (int j2 = 0; j2 < 4; ++j2) {
        const int r = wn * 64 + j2 * 16 + (lane & 15);
        const int g = (kk * 4 + (lane >> 4)) ^ (r & 7);
        fb[j2] = *(const bf16x8*)((const char*)Bh + r * 128 + g * 16);
      }
#pragma unroll
      for (int j2 = 0; j2 < 4; ++j2)
#pragma unroll
        for (int i = 0; i < 4; ++i)
          acc[j2][i] = __builtin_amdgcn_mfma_f32_16x16x32_bf16(fb[j2], fa[i], acc[j2][i], 0, 0, 0);
    }
    __syncthreads();
  }

  // linear dump: 1 KB contiguous per wave-instr, 16 KB per wave, 64 KB per block
  float* dbase = g_dots + (size_t)(tile_r * 64 + tile_c) * 16384 + (size_t)wid * 4096 + lane * 4;
#pragma unroll
  for (int j = 0; j < 4; ++j)
#pragma unroll
    for (int i = 0; i < 4; ++i)
      *(f32x4*)(dbase + (j * 4 + i) * 256) = acc[j][i];
}

// ---------------------------------------------------------------------------
// Kernel 2b: streaming epilogue. Block = one att row; thread t handles
// float4s f = k*256 + t (k=0..7) -> per wave-instr 1 KB contiguous read-side
// window (16B gathers, L3-hot) and 1 KB contiguous att stores; per-wave
// store stream is 4 KB-contiguous blocks sweeping the full 32 KB row.
// Math = exact reference f32 rounding sequence (unchanged).
// ---------------------------------------------------------------------------
__global__ __launch_bounds__(256) void att_stream(const float* __restrict__ mus,
                                                  float* __restrict__ att) {
  const int ar  = blockIdx.x;
  const int tid = threadIdx.x;
  const int tile_r = ar >> 7;
  const int a   = ar & 127;
  const int wm  = a >> 6;
  const int i_  = (a >> 4) & 3;
  const int l15 = a & 15;
  const float zz = g_z2[ar];
  float* dst = att + (size_t)ar * NC;

#pragma unroll
  for (int k = 0; k < 8; ++k) {
    const int f  = k * 256 + tid;
    const int cg = f * 4;
    const int tile_c = cg >> 7;
    const int c  = cg & 127;
    const int wn = c >> 6;
    const int j_ = (c >> 4) & 3;
    const int q  = (c >> 2) & 3;
    const size_t off = (size_t)(tile_r * 64 + tile_c) * 16384 +
                       (size_t)((wm * 2 + wn) * 16 + j_ * 4 + i_) * 256 +
                       (q * 16 + l15) * 4;
    const float4 dv = *(const float4*)(g_dots + off);
    const float4 cc = *(const float4*)(g_c2 + cg);
    const float4 mu = *(const float4*)(mus + cg);
    const float dvv[4] = {dv.x, dv.y, dv.z, dv.w};
    const float ccv[4] = {cc.x, cc.y, cc.z, cc.w};
    const float muv[4] = {mu.x, mu.y, mu.z, mu.w};
    float o[4];
#pragma unroll
    for (int r = 0; r < 4; ++r) {
      float tt  = __fadd_rn(zz, ccv[r]);
      float sq  = __fsub_rn(tt, __fmul_rn(2.0f, dvv[r]));
      float d   = sqrtf(fmaxf(sq, 0.0f));
      float den = __fadd_rn(__fmul_rn(d, d), 1e-6f);
      o[r] = __fdiv_rn(muv[r], den);
    }
    *(float4*)(dst + cg) = *(const float4*)o;
  }
}

// ---------------------------------------------------------------------------
// Kernel 3: wave-per-row top-NCAND via packed-key pop-lists (unchanged).
// ---------------------------------------------------------------------------
__global__ __launch_bounds__(256, 4) void topk_kernel(const float* __restrict__ att,
                                                      const float* __restrict__ z,
                                                      const float* __restrict__ centers,
                                                      const float* __restrict__ mus,
                                                      float* __restrict__ out) {
  __shared__ int selLds[4][16];
  const int lane = threadIdx.x & 63;
  const int wv   = threadIdx.x >> 6;
  const int row  = blockIdx.x * 4 + wv;
  const float4* arow4 = (const float4*)(att + (size_t)row * NC);

  u64 k[8][4];
#pragma unroll
  for (int c = 0; c < 8; ++c) {
#pragma unroll
    for (int j = 0; j < 4; ++j) k[c][j] = 0ull;
#pragma unroll
    for (int qq = 0; qq < 4; ++qq) {
      float4 v4 = arow4[c * 256 + qq * 64 + lane];
      const unsigned ib = (unsigned)(c * 1024 + qq * 256 + lane * 4);
      const float vv[4] = {v4.x, v4.y, v4.z, v4.w};
#pragma unroll
      for (int e = 0; e < 4; ++e) {
        u64 nk = ((u64)__float_as_uint(vv[e]) << 32) | (u64)(0xFFFFFFFFu - (ib + e));
        bool g0 = nk > k[c][0], g1 = nk > k[c][1], g2 = nk > k[c][2], g3 = nk > k[c][3];
        u64 t0 = k[c][0], t1 = k[c][1], t2 = k[c][2];
        k[c][0] = g0 ? nk : k[c][0];
        k[c][1] = g0 ? t0 : (g1 ? nk : k[c][1]);
        k[c][2] = g1 ? t1 : (g2 ? nk : k[c][2]);
        k[c][3] = g2 ? t2 : (g3 ? nk : k[c][3]);
      }
    }
  }

  for (int it = 0; it < NCAND; ++it) {
    u64 b = k[0][0];
#pragma unroll
    for (int c = 1; c < 8; ++c) b = (k[c][0] > b) ? k[c][0] : b;
#pragma unroll
    for (int off = 32; off > 0; off >>= 1) {
      u64 o = __shfl_xor(b, off);
      b = (o > b) ? o : b;
    }
    if (lane == 0) selLds[wv][it] = (int)(0xFFFFFFFFu - (unsigned)(b & 0xFFFFFFFFu));
#pragma unroll
    for (int c = 0; c < 8; ++c) {
      bool hit = (k[c][0] == b);
      k[c][0] = hit ? k[c][1] : k[c][0];
      k[c][1] = hit ? k[c][2] : k[c][1];
      k[c][2] = hit ? k[c][3] : k[c][2];
      k[c][3] = hit ? 0ull    : k[c][3];
    }
  }

  const float* zrow = z + (size_t)row * DIM;
  const int d0 = lane * 8;
  const float4 za = *(const float4*)(zrow + d0);
  const float4 zb = *(const float4*)(zrow + d0 + 4);
  const float myz2 = g_z2[row];

  double p[NCAND];
  int cidx[NCAND];
#pragma unroll
  for (int c = 0; c < NCAND; ++c) {
    cidx[c] = selLds[wv][c];
    const float* cp = centers + (size_t)cidx[c] * DIM + d0;
    float4 ca = *(const float4*)(cp);
    float4 cb = *(const float4*)(cp + 4);
    p[c] = (double)za.x * ca.x + (double)za.y * ca.y +
           (double)za.z * ca.z + (double)za.w * ca.w +
           (double)zb.x * cb.x + (double)zb.y * cb.y +
           (double)zb.z * cb.z + (double)zb.w * cb.w;
  }
#pragma unroll
  for (int off = 32; off > 0; off >>= 1) {
#pragma unroll
    for (int c = 0; c < NCAND; ++c) p[c] += __shfl_xor(p[c], off);
  }

  float exv[NCAND];
#pragma unroll
  for (int c = 0; c < NCAND; ++c) {
    const int ci = cidx[c];
    float dotf = (float)p[c];
    float t   = __fadd_rn(myz2, g_c2[ci]);
    float sq  = __fsub_rn(t, __fmul_rn(2.0f, dotf));
    float d   = sqrtf(fmaxf(sq, 0.0f));
    float den = __fadd_rn(__fmul_rn(d, d), 1e-6f);
    exv[c] = __fdiv_rn(mus[ci], den);
  }

  unsigned used = 0;
  float tv[KEXP]; int tix[KEXP];
#pragma unroll
  for (int s = 0; s < KEXP; ++s) {
    float bv = -INFINITY; int bi = 0x7FFFFFFF; int bc = 0;
#pragma unroll
    for (int c = 0; c < NCAND; ++c) {
      bool ok = (used & (1u << c)) == 0;
      if (ok && (exv[c] > bv || (exv[c] == bv && cidx[c] < bi))) {
        bv = exv[c]; bi = cidx[c]; bc = c;
      }
    }
    used |= (1u << bc);
    tv[s] = bv; tix[s] = bi;
  }

  float mm = tv[0];
  float w[KEXP];
  float s = 0.0f;
#pragma unroll
  for (int kk = 0; kk < KEXP; ++kk) { w[kk] = expf(tv[kk] - mm); s += w[kk]; }
#pragma unroll
  for (int kk = 0; kk < KEXP; ++kk) w[kk] /= s;

  float comb[8] = {0, 0, 0, 0, 0, 0, 0, 0};
#pragma unroll
  for (int kk = 0; kk < KEXP; ++kk) {
    const float* cp = centers + (size_t)tix[kk] * DIM + d0;
    float4 a = *(const float4*)(cp);
    float4 bq = *(const float4*)(cp + 4);
    comb[0] += w[kk] * a.x;  comb[1] += w[kk] * a.y;
    comb[2] += w[kk] * a.z;  comb[3] += w[kk] * a.w;
    comb[4] += w[kk] * bq.x; comb[5] += w[kk] * bq.y;
    comb[6] += w[kk] * bq.z; comb[7] += w[kk] * bq.w;
  }
  const float zv[8] = {za.x, za.y, za.z, za.w, zb.x, zb.y, zb.z, zb.w};
  float o[8];
#pragma unroll
  for (int e = 0; e < 8; ++e)
    o[e] = __fadd_rn(__fmul_rn(0.7f, zv[e]), __fmul_rn(0.3f, comb[e]));
  *(float4*)(out + (size_t)row * DIM + d0)     = *(float4*)&o[0];
  *(float4*)(out + (size_t)row * DIM + d0 + 4) = *(float4*)&o[4];
}

// ---------------------------------------------------------------------------
extern "C" void kernel_launch(void* const* d_in, const int* in_sizes, int n_in,
                              void* d_out, int out_size, void* d_ws, size_t ws_size,
                              hipStream_t stream) {
  const float* z       = (const float*)d_in[0];
  const float* centers = (const float*)d_in[1];
  const float* mus     = (const float*)d_in[2];
  float* out      = (float*)d_out;
  float* expanded = out;
  float* att      = out + (size_t)BATCH * DIM;

  convert_kernel<<<(BATCH + NC) * DIM / (256 * 8), 256, 0, stream>>>(z, centers);
  gemm_dots<<<(BATCH / BM) * (NC / BN), 256, 0, stream>>>();
  att_stream<<<BATCH, 256, 0, stream>>>(mus, att);
  topk_kernel<<<BATCH / 4, 256, 0, stream>>>(att, z, centers, mus, expanded);
}

// Round 12
// 198.094 us; speedup vs baseline: 1.5516x; 1.5516x over previous
//
#include <hip/hip_runtime.h>
#include <math.h>

#define BATCH 4096
#define NC    8192
#define DIM   512
#define KEXP  5
#define NCAND 10

using bf16x8 = __attribute__((ext_vector_type(8))) short;
using f32x4  = __attribute__((ext_vector_type(4))) float;
typedef unsigned long long u64;

__device__ unsigned short g_zbf[BATCH * DIM];   // 4 MB bf16(z)
__device__ unsigned short g_cbf[NC * DIM];      // 8 MB bf16(centers)
__device__ float g_z2[BATCH];
__device__ float g_c2[NC];

__device__ __forceinline__ unsigned short rtne_bf16(float f) {
  unsigned u = __float_as_uint(f);
  u += 0x7FFFu + ((u >> 16) & 1u);
  return (unsigned short)(u >> 16);
}

__device__ __forceinline__ void gload16(const void* g, void* l) {
  __builtin_amdgcn_global_load_lds(
      (const __attribute__((address_space(1))) void*)g,
      (__attribute__((address_space(3))) void*)l, 16, 0, 0);
}

// ---------------------------------------------------------------------------
// Kernel 0: f32 -> bf16 (RTN) conversion FUSED with f64 row-norms.
// ---------------------------------------------------------------------------
__global__ __launch_bounds__(256) void convert_kernel(const float* __restrict__ z,
                                                      const float* __restrict__ c) {
  const size_t i = ((size_t)blockIdx.x * 256 + threadIdx.x) * 8;
  const size_t zn = (size_t)BATCH * DIM;
  const float* src;
  unsigned short* dst;
  float* ndst;
  size_t off;
  if (i < zn) { src = z; dst = g_zbf; ndst = g_z2; off = i; }
  else        { src = c; dst = g_cbf; ndst = g_c2; off = i - zn; }
  float4 a = *(const float4*)(src + off);
  float4 b = *(const float4*)(src + off + 4);
  uint4 o;
  o.x = (unsigned)rtne_bf16(a.x) | ((unsigned)rtne_bf16(a.y) << 16);
  o.y = (unsigned)rtne_bf16(a.z) | ((unsigned)rtne_bf16(a.w) << 16);
  o.z = (unsigned)rtne_bf16(b.x) | ((unsigned)rtne_bf16(b.y) << 16);
  o.w = (unsigned)rtne_bf16(b.z) | ((unsigned)rtne_bf16(b.w) << 16);
  *(uint4*)(dst + off) = o;

  double s = (double)a.x * a.x + (double)a.y * a.y + (double)a.z * a.z + (double)a.w * a.w +
             (double)b.x * b.x + (double)b.y * b.y + (double)b.z * b.z + (double)b.w * b.w;
#pragma unroll
  for (int sh = 32; sh > 0; sh >>= 1) s += __shfl_xor(s, sh);
  if ((threadIdx.x & 63) == 0) ndst[off / DIM] = (float)s;
}

// ---------------------------------------------------------------------------
// Kernel 2: attractions GEMM, 256x256 tile, BK=64, 8 waves, double-buffered
// 128 KB LDS, COUNTED-vmcnt pipeline (T4): prologue stages tiles 0,1; each
// iter k: s_waitcnt vmcnt(8) (drain ONLY tile k's 8 loads; tile k+1's stay
// in flight) -> raw s_barrier -> ds_read+MFMA (setprio, T5) -> raw s_barrier
// -> STAGE(k+2) into the just-read buffer. Never vmcnt(0) in the main loop.
// Numerics/swizzle/epilogue identical to the validated round-9 kernel.
// ---------------------------------------------------------------------------
#define BMT 256
#define BNT 256
#define BKT 64

__global__ __launch_bounds__(512) void attr_bf16(const float* __restrict__ mus,
                                                 float* __restrict__ att) {
  __shared__ __align__(16) unsigned short Ab[2][BMT * BKT];  // 32 KB each
  __shared__ __align__(16) unsigned short Bb[2][BMT * BKT];  // total 128 KB

  const int tid  = threadIdx.x;
  const int lane = tid & 63;
  const int wv   = tid >> 6;        // 0..7
  const int wm   = wv >> 2;         // 0..1  (M half: 128 rows)
  const int wn   = wv & 3;          // 0..3  (N quarter: 64 cols)
  const int l15  = lane & 15;
  const int q    = lane >> 4;       // 0..3

  // XCD strip: 2 tile-rows x 32 tile-cols per XCD, column-major walk
  const int flat = blockIdx.x;      // 512 blocks
  const int xcd  = flat & 7;
  const int tt   = flat >> 3;       // 0..63
  const int row0 = (xcd * 2 + (tt & 1)) * BMT;
  const int col0 = (tt >> 1) * BNT;

  const unsigned short* Ag = g_zbf + (size_t)row0 * DIM;
  const unsigned short* Bg = g_cbf + (size_t)col0 * DIM;

  const int crow = lane >> 3;            // 0..7
  const int sg   = (lane & 7) ^ crow;    // pre-swizzled source granule

  f32x4 acc[8][4] = {};

#define STAGE(S, B)                                                          \
  {                                                                          \
    const int k0_ = (S) * BKT;                                               \
    _Pragma("unroll")                                                        \
    for (int inst = 0; inst < 4; ++inst) {                                   \
      const int r_ = wv * 32 + inst * 8 + crow;                              \
      gload16(Ag + (size_t)r_ * DIM + k0_ + sg * 8,                          \
              &Ab[B][(wv * 32 + inst * 8) * 64]);                            \
      gload16(Bg + (size_t)r_ * DIM + k0_ + sg * 8,                          \
              &Bb[B][(wv * 32 + inst * 8) * 64]);                            \
    }                                                                        \
  }

#define COMPUTE(B)                                                           \
  {                                                                          \
    _Pragma("unroll")                                                        \
    for (int kk = 0; kk < 2; ++kk) {                                         \
      const int gq = (kk * 4 + q) ^ (lane & 7);                              \
      bf16x8 fa[8], fb[4];                                                   \
      _Pragma("unroll")                                                      \
      for (int i = 0; i < 8; ++i) {                                          \
        const int r = wm * 128 + i * 16 + l15;                               \
        fa[i] = *(const bf16x8*)(&Ab[B][r * 64 + gq * 8]);                   \
      }                                                                      \
      _Pragma("unroll")                                                      \
      for (int j = 0; j < 4; ++j) {                                          \
        const int r = wn * 64 + j * 16 + l15;                                \
        fb[j] = *(const bf16x8*)(&Bb[B][r * 64 + gq * 8]);                   \
      }                                                                      \
      __builtin_amdgcn_s_setprio(1);                                         \
      _Pragma("unroll")                                                      \
      for (int i = 0; i < 8; ++i)                                            \
        _Pragma("unroll")                                                    \
        for (int j = 0; j < 4; ++j)                                          \
          acc[i][j] = __builtin_amdgcn_mfma_f32_16x16x32_bf16(fb[j], fa[i],  \
                                                              acc[i][j], 0, 0, 0); \
      __builtin_amdgcn_s_setprio(0);                                         \
    }                                                                        \
  }

  // prologue: two tiles in flight
  STAGE(0, 0);
  STAGE(1, 1);

  for (int k = 0; k < 8; ++k) {
    const int cur = k & 1;
    if (k == 7) { asm volatile("s_waitcnt vmcnt(0)" ::: "memory"); }
    else        { asm volatile("s_waitcnt vmcnt(8)" ::: "memory"); }
    __builtin_amdgcn_s_barrier();   // tile k landed for ALL waves
    COMPUTE(cur);
    __builtin_amdgcn_s_barrier();   // all waves done reading buf[cur]
    if (k < 6) STAGE(k + 2, cur);   // overwrite just-read buffer; stays in flight
  }
#undef STAGE
#undef COMPUTE

  // epilogue: validated mapping + dwordx4 stores
#pragma unroll
  for (int i = 0; i < 8; ++i) {
    const int ar = row0 + wm * 128 + i * 16 + l15;
    const float zz = g_z2[ar];
    float* dst = att + (size_t)ar * NC;
#pragma unroll
    for (int j = 0; j < 4; ++j) {
      const int gc0 = col0 + wn * 64 + j * 16 + q * 4;
      const float4 cc = *(const float4*)&g_c2[gc0];
      const float4 mu = *(const float4*)&mus[gc0];
      const float ccv[4] = {cc.x, cc.y, cc.z, cc.w};
      const float muv[4] = {mu.x, mu.y, mu.z, mu.w};
      float o[4];
#pragma unroll
      for (int r = 0; r < 4; ++r) {
        float ttv = __fadd_rn(zz, ccv[r]);
        float sq  = __fsub_rn(ttv, __fmul_rn(2.0f, acc[i][j][r]));
        float d   = sqrtf(fmaxf(sq, 0.0f));
        float den = __fadd_rn(__fmul_rn(d, d), 1e-6f);
        o[r] = __fdiv_rn(muv[r], den);
      }
      *(float4*)(dst + gc0) = *(const float4*)o;
    }
  }
}

// ---------------------------------------------------------------------------
// Kernel 3: wave-per-row top-NCAND via packed-key pop-lists (unchanged).
// ---------------------------------------------------------------------------
__global__ __launch_bounds__(256, 4) void topk_kernel(const float* __restrict__ att,
                                                      const float* __restrict__ z,
                                                      const float* __restrict__ centers,
                                                      const float* __restrict__ mus,
                                                      float* __restrict__ out) {
  __shared__ int selLds[4][16];
  const int lane = threadIdx.x & 63;
  const int wv   = threadIdx.x >> 6;
  const int row  = blockIdx.x * 4 + wv;
  const float4* arow4 = (const float4*)(att + (size_t)row * NC);

  u64 k[8][4];
#pragma unroll
  for (int c = 0; c < 8; ++c) {
#pragma unroll
    for (int j = 0; j < 4; ++j) k[c][j] = 0ull;
#pragma unroll
    for (int qq = 0; qq < 4; ++qq) {
      float4 v4 = arow4[c * 256 + qq * 64 + lane];
      const unsigned ib = (unsigned)(c * 1024 + qq * 256 + lane * 4);
      const float vv[4] = {v4.x, v4.y, v4.z, v4.w};
#pragma unroll
      for (int e = 0; e < 4; ++e) {
        u64 nk = ((u64)__float_as_uint(vv[e]) << 32) | (u64)(0xFFFFFFFFu - (ib + e));
        bool g0 = nk > k[c][0], g1 = nk > k[c][1], g2 = nk > k[c][2], g3 = nk > k[c][3];
        u64 t0 = k[c][0], t1 = k[c][1], t2 = k[c][2];
        k[c][0] = g0 ? nk : k[c][0];
        k[c][1] = g0 ? t0 : (g1 ? nk : k[c][1]);
        k[c][2] = g1 ? t1 : (g2 ? nk : k[c][2]);
        k[c][3] = g2 ? t2 : (g3 ? nk : k[c][3]);
      }
    }
  }

  for (int it = 0; it < NCAND; ++it) {
    u64 b = k[0][0];
#pragma unroll
    for (int c = 1; c < 8; ++c) b = (k[c][0] > b) ? k[c][0] : b;
#pragma unroll
    for (int off = 32; off > 0; off >>= 1) {
      u64 o = __shfl_xor(b, off);
      b = (o > b) ? o : b;
    }
    if (lane == 0) selLds[wv][it] = (int)(0xFFFFFFFFu - (unsigned)(b & 0xFFFFFFFFu));
#pragma unroll
    for (int c = 0; c < 8; ++c) {
      bool hit = (k[c][0] == b);
      k[c][0] = hit ? k[c][1] : k[c][0];
      k[c][1] = hit ? k[c][2] : k[c][1];
      k[c][2] = hit ? k[c][3] : k[c][2];
      k[c][3] = hit ? 0ull    : k[c][3];
    }
  }

  const float* zrow = z + (size_t)row * DIM;
  const int d0 = lane * 8;
  const float4 za = *(const float4*)(zrow + d0);
  const float4 zb = *(const float4*)(zrow + d0 + 4);
  const float myz2 = g_z2[row];

  double p[NCAND];
  int cidx[NCAND];
#pragma unroll
  for (int c = 0; c < NCAND; ++c) {
    cidx[c] = selLds[wv][c];
    const float* cp = centers + (size_t)cidx[c] * DIM + d0;
    float4 ca = *(const float4*)(cp);
    float4 cb = *(const float4*)(cp + 4);
    p[c] = (double)za.x * ca.x + (double)za.y * ca.y +
           (double)za.z * ca.z + (double)za.w * ca.w +
           (double)zb.x * cb.x + (double)zb.y * cb.y +
           (double)zb.z * cb.z + (double)zb.w * cb.w;
  }
#pragma unroll
  for (int off = 32; off > 0; off >>= 1) {
#pragma unroll
    for (int c = 0; c < NCAND; ++c) p[c] += __shfl_xor(p[c], off);
  }

  float exv[NCAND];
#pragma unroll
  for (int c = 0; c < NCAND; ++c) {
    const int ci = cidx[c];
    float dotf = (float)p[c];
    float t   = __fadd_rn(myz2, g_c2[ci]);
    float sq  = __fsub_rn(t, __fmul_rn(2.0f, dotf));
    float d   = sqrtf(fmaxf(sq, 0.0f));
    float den = __fadd_rn(__fmul_rn(d, d), 1e-6f);
    exv[c] = __fdiv_rn(mus[ci], den);
  }

  unsigned used = 0;
  float tv[KEXP]; int tix[KEXP];
#pragma unroll
  for (int s = 0; s < KEXP; ++s) {
    float bv = -INFINITY; int bi = 0x7FFFFFFF; int bc = 0;
#pragma unroll
    for (int c = 0; c < NCAND; ++c) {
      bool ok = (used & (1u << c)) == 0;
      if (ok && (exv[c] > bv || (exv[c] == bv && cidx[c] < bi))) {
        bv = exv[c]; bi = cidx[c]; bc = c;
      }
    }
    used |= (1u << bc);
    tv[s] = bv; tix[s] = bi;
  }

  float mm = tv[0];
  float w[KEXP];
  float s = 0.0f;
#pragma unroll
  for (int kk = 0; kk < KEXP; ++kk) { w[kk] = expf(tv[kk] - mm); s += w[kk]; }
#pragma unroll
  for (int kk = 0; kk < KEXP; ++kk) w[kk] /= s;

  float comb[8] = {0, 0, 0, 0, 0, 0, 0, 0};
#pragma unroll
  for (int kk = 0; kk < KEXP; ++kk) {
    const float* cp = centers + (size_t)tix[kk] * DIM + d0;
    float4 a = *(const float4*)(cp);
    float4 bq = *(const float4*)(cp + 4);
    comb[0] += w[kk] * a.x;  comb[1] += w[kk] * a.y;
    comb[2] += w[kk] * a.z;  comb[3] += w[kk] * a.w;
    comb[4] += w[kk] * bq.x; comb[5] += w[kk] * bq.y;
    comb[6] += w[kk] * bq.z; comb[7] += w[kk] * bq.w;
  }
  const float zv[8] = {za.x, za.y, za.z, za.w, zb.x, zb.y, zb.z, zb.w};
  float o[8];
#pragma unroll
  for (int e = 0; e < 8; ++e)
    o[e] = __fadd_rn(__fmul_rn(0.7f, zv[e]), __fmul_rn(0.3f, comb[e]));
  *(float4*)(out + (size_t)row * DIM + d0)     = *(float4*)&o[0];
  *(float4*)(out + (size_t)row * DIM + d0 + 4) = *(float4*)&o[4];
}

// ---------------------------------------------------------------------------
extern "C" void kernel_launch(void* const* d_in, const int* in_sizes, int n_in,
                              void* d_out, int out_size, void* d_ws, size_t ws_size,
                              hipStream_t stream) {
  const float* z       = (const float*)d_in[0];
  const float* centers = (const float*)d_in[1];
  const float* mus     = (const float*)d_in[2];
  float* out      = (float*)d_out;
  float* expanded = out;
  float* att      = out + (size_t)BATCH * DIM;

  convert_kernel<<<(BATCH + NC) * DIM / (256 * 8), 256, 0, stream>>>(z, centers);
  attr_bf16<<<(BATCH / BMT) * (NC / BNT), 512, 0, stream>>>(mus, att);
  topk_kernel<<<BATCH / 4, 256, 0, stream>>>(att, z, centers, mus, expanded);
}